// Round 1
// baseline (1160.657 us; speedup 1.0000x reference)
//
#include <hip/hip_runtime.h>

// Problem constants
#define NB    8      // batch
#define CDIM  768    // channels
#define NTOK  1024   // tokens = 32*32
#define NHEAD 12
#define DHEAD 64
#define C3    2304   // 3*CDIM
#define NTH   36     // 3*NHEAD (t*12+h)

// ---------------------------------------------------------------------------
// Kernel 0: repack w_qkv[c][d*36 + t*12 + h] -> B2[c][th*64 + d]
// so the QKV GEMM has plain row-major B with coalesced loads, and output
// columns map to contiguous d within one (t,h).
// ---------------------------------------------------------------------------
__global__ void repack_w(const float* __restrict__ w, float* __restrict__ b2) {
    int g = blockIdx.x * 256 + threadIdx.x;
    if (g >= CDIM * C3) return;
    int c = g / C3;
    int r = g - c * C3;
    int th = r >> 6;          // which (t,h)
    int d  = r & 63;
    b2[g] = w[c * C3 + d * 36 + th];
}

// ---------------------------------------------------------------------------
// Kernel 1: QKV GEMM.  M=8192 (b,p), K=768, N=2304 (th,d).
// A[m][k] = x[b][k][p]  (contiguous in m -> coalesced row loads into LDS)
// B2 row-major.  BM=128 BN=128 BK=16, 256 threads, 8x8 microtile.
// Output scattered to Q/K/V [(b*12+h)][p][d], coalesced per 64-wide d run.
// ---------------------------------------------------------------------------
__launch_bounds__(256)
__global__ void qkv_gemm(const float* __restrict__ x, const float* __restrict__ b2,
                         float* __restrict__ q, float* __restrict__ k,
                         float* __restrict__ v) {
    __shared__ float As[16][128];
    __shared__ float Bs[16][128];

    const int tid = threadIdx.x;
    const int tx = tid & 15, ty = tid >> 4;
    const int m0 = blockIdx.x * 128;
    const int n0 = blockIdx.y * 128;
    const int b  = m0 >> 10;          // batch (tile never straddles batches)
    const int p0 = m0 & 1023;

    const float* xb = x + (size_t)b * CDIM * NTOK;

    float acc[8][8] = {};

    for (int k0 = 0; k0 < CDIM; k0 += 16) {
        // load A tile (16x128) and B tile (16x128): 512 float4 each, 2/thread
        #pragma unroll
        for (int i = 0; i < 2; ++i) {
            int idx = tid + i * 256;          // [0,512)
            int kk = idx >> 5;                // 0..15
            int c4 = (idx & 31) * 4;          // 0..124
            float4 av = *(const float4*)&xb[(size_t)(k0 + kk) * NTOK + p0 + c4];
            *(float4*)&As[kk][c4] = av;
            float4 bv = *(const float4*)&b2[(size_t)(k0 + kk) * C3 + n0 + c4];
            *(float4*)&Bs[kk][c4] = bv;
        }
        __syncthreads();

        #pragma unroll
        for (int kk = 0; kk < 16; ++kk) {
            float4 a0 = *(const float4*)&As[kk][ty * 8];
            float4 a1 = *(const float4*)&As[kk][ty * 8 + 4];
            float4 b0 = *(const float4*)&Bs[kk][tx * 8];
            float4 b1 = *(const float4*)&Bs[kk][tx * 8 + 4];
            float a[8] = {a0.x, a0.y, a0.z, a0.w, a1.x, a1.y, a1.z, a1.w};
            float bb[8] = {b0.x, b0.y, b0.z, b0.w, b1.x, b1.y, b1.z, b1.w};
            #pragma unroll
            for (int i = 0; i < 8; ++i)
                #pragma unroll
                for (int j = 0; j < 8; ++j)
                    acc[i][j] = fmaf(a[i], bb[j], acc[i][j]);
        }
        __syncthreads();
    }

    // store: this thread's 8 columns lie inside one (t,h) since 8 | 64
    const int np = n0 + tx * 8;
    const int th = np >> 6;           // 0..35
    const int db = np & 63;
    const int t  = th / 12;
    const int h  = th - t * 12;
    float* dst = (t == 0 ? q : (t == 1 ? k : v)) + ((size_t)(b * 12 + h) * NTOK) * DHEAD;
    #pragma unroll
    for (int i = 0; i < 8; ++i) {
        int p = p0 + ty * 8 + i;
        *(float4*)&dst[(size_t)p * DHEAD + db] =
            make_float4(acc[i][0], acc[i][1], acc[i][2], acc[i][3]);
        *(float4*)&dst[(size_t)p * DHEAD + db + 4] =
            make_float4(acc[i][4], acc[i][5], acc[i][6], acc[i][7]);
    }
}

// ---------------------------------------------------------------------------
// Kernel 2: flash-style attention per (b,h).  64 q-rows per block,
// 16 kv-tiles of 64.  Online softmax; row groups = 16 consecutive lanes.
// energy = (q*8) . k  (reference MULTIPLIES by sqrt(d_head)=8).
// ---------------------------------------------------------------------------
__launch_bounds__(256)
__global__ void attn_kernel(const float* __restrict__ q, const float* __restrict__ k,
                            const float* __restrict__ v, float* __restrict__ ctx) {
    __shared__ float Qs[64][68];
    __shared__ float Ks[64][68];
    __shared__ float Vs[64][68];
    __shared__ float Ps[64][68];

    const int tid = threadIdx.x;
    const int tx = tid & 15, ty = tid >> 4;
    const int bh = blockIdx.y;            // 0..95
    const int p0 = blockIdx.x * 64;

    const float* Qb = q + (size_t)bh * NTOK * DHEAD;
    const float* Kb = k + (size_t)bh * NTOK * DHEAD;
    const float* Vb = v + (size_t)bh * NTOK * DHEAD;

    // load Q tile, pre-scaled by 8
    #pragma unroll
    for (int i = 0; i < 4; ++i) {
        int idx = tid + i * 256;          // [0,1024) float4s
        int m = idx >> 4;
        int d4 = (idx & 15) * 4;
        float4 t4 = *(const float4*)&Qb[(size_t)(p0 + m) * DHEAD + d4];
        t4.x *= 8.f; t4.y *= 8.f; t4.z *= 8.f; t4.w *= 8.f;
        *(float4*)&Qs[m][d4] = t4;
    }

    float o[4][4] = {};
    float mo[4] = {-3.0e38f, -3.0e38f, -3.0e38f, -3.0e38f};
    float l[4]  = {0.f, 0.f, 0.f, 0.f};

    for (int kt = 0; kt < 16; ++kt) {
        __syncthreads();   // previous PV done before overwriting K/V
        #pragma unroll
        for (int i = 0; i < 4; ++i) {
            int idx = tid + i * 256;
            int m = idx >> 4;
            int d4 = (idx & 15) * 4;
            *(float4*)&Ks[m][d4] = *(const float4*)&Kb[(size_t)(kt * 64 + m) * DHEAD + d4];
            *(float4*)&Vs[m][d4] = *(const float4*)&Vb[(size_t)(kt * 64 + m) * DHEAD + d4];
        }
        __syncthreads();

        // S = Qs . Ks^T   (4x4 per thread: rows ty*4.., cols tx*4..)
        float s[4][4] = {};
        #pragma unroll
        for (int kd = 0; kd < 64; kd += 4) {
            float4 qv[4], kv[4];
            #pragma unroll
            for (int i = 0; i < 4; ++i) qv[i] = *(const float4*)&Qs[ty * 4 + i][kd];
            #pragma unroll
            for (int j = 0; j < 4; ++j) kv[j] = *(const float4*)&Ks[tx * 4 + j][kd];
            #pragma unroll
            for (int i = 0; i < 4; ++i)
                #pragma unroll
                for (int j = 0; j < 4; ++j) {
                    s[i][j] = fmaf(qv[i].x, kv[j].x, s[i][j]);
                    s[i][j] = fmaf(qv[i].y, kv[j].y, s[i][j]);
                    s[i][j] = fmaf(qv[i].z, kv[j].z, s[i][j]);
                    s[i][j] = fmaf(qv[i].w, kv[j].w, s[i][j]);
                }
        }

        // online softmax update
        float f[4];
        #pragma unroll
        for (int i = 0; i < 4; ++i) {
            float mt = fmaxf(fmaxf(s[i][0], s[i][1]), fmaxf(s[i][2], s[i][3]));
            #pragma unroll
            for (int off = 1; off < 16; off <<= 1)
                mt = fmaxf(mt, __shfl_xor(mt, off, 16));
            float mn = fmaxf(mo[i], mt);
            f[i] = __expf(mo[i] - mn);
            mo[i] = mn;
        }
        #pragma unroll
        for (int i = 0; i < 4; ++i) {
            float rs = 0.f;
            #pragma unroll
            for (int j = 0; j < 4; ++j) {
                s[i][j] = __expf(s[i][j] - mo[i]);
                rs += s[i][j];
            }
            #pragma unroll
            for (int off = 1; off < 16; off <<= 1)
                rs += __shfl_xor(rs, off, 16);
            l[i] = l[i] * f[i] + rs;
            #pragma unroll
            for (int j = 0; j < 4; ++j) o[i][j] *= f[i];
            *(float4*)&Ps[ty * 4 + i][tx * 4] =
                make_float4(s[i][0], s[i][1], s[i][2], s[i][3]);
        }
        __syncthreads();

        // O += P . V   (rows ty*4.., d-cols tx*4..)
        #pragma unroll
        for (int j = 0; j < 64; ++j) {
            float4 vv = *(const float4*)&Vs[j][tx * 4];
            float pb0 = Ps[ty * 4 + 0][j];
            float pb1 = Ps[ty * 4 + 1][j];
            float pb2 = Ps[ty * 4 + 2][j];
            float pb3 = Ps[ty * 4 + 3][j];
            o[0][0] = fmaf(pb0, vv.x, o[0][0]); o[0][1] = fmaf(pb0, vv.y, o[0][1]);
            o[0][2] = fmaf(pb0, vv.z, o[0][2]); o[0][3] = fmaf(pb0, vv.w, o[0][3]);
            o[1][0] = fmaf(pb1, vv.x, o[1][0]); o[1][1] = fmaf(pb1, vv.y, o[1][1]);
            o[1][2] = fmaf(pb1, vv.z, o[1][2]); o[1][3] = fmaf(pb1, vv.w, o[1][3]);
            o[2][0] = fmaf(pb2, vv.x, o[2][0]); o[2][1] = fmaf(pb2, vv.y, o[2][1]);
            o[2][2] = fmaf(pb2, vv.z, o[2][2]); o[2][3] = fmaf(pb2, vv.w, o[2][3]);
            o[3][0] = fmaf(pb3, vv.x, o[3][0]); o[3][1] = fmaf(pb3, vv.y, o[3][1]);
            o[3][2] = fmaf(pb3, vv.z, o[3][2]); o[3][3] = fmaf(pb3, vv.w, o[3][3]);
        }
    }

    // epilogue: ctx[b][p][h*64+d] = O / l
    const int b = bh / 12;
    const int h = bh - b * 12;
    #pragma unroll
    for (int i = 0; i < 4; ++i) {
        float inv = 1.f / l[i];
        int p = p0 + ty * 4 + i;
        *(float4*)&ctx[((size_t)(b * NTOK + p)) * CDIM + h * DHEAD + tx * 4] =
            make_float4(o[i][0] * inv, o[i][1] * inv, o[i][2] * inv, o[i][3] * inv);
    }
}

// ---------------------------------------------------------------------------
// Kernel 3: proj GEMM.  M=8192, K=768, N=768.  BM=128 BN=64 BK=16,
// 256 threads, 8x4 microtile.  LDS-transpose epilogue for coalesced
// transposed store to d_out[b][c'][p].
// ---------------------------------------------------------------------------
__launch_bounds__(256)
__global__ void proj_gemm(const float* __restrict__ ctx, const float* __restrict__ w,
                          float* __restrict__ out) {
    __shared__ float As[16][132];    // [k][m], padded
    __shared__ float Bs[16][64];     // [k][n]
    __shared__ float Tr[64][132];    // transpose buffer [n][m], padded

    const int tid = threadIdx.x;
    const int tx = tid & 15, ty = tid >> 4;
    const int m0 = blockIdx.x * 128;
    const int n0 = blockIdx.y * 64;
    const int b  = m0 >> 10;
    const int p0 = m0 & 1023;

    float acc[8][4] = {};

    for (int k0 = 0; k0 < CDIM; k0 += 16) {
        // A tile: ctx rows are contiguous in k -> load f4 along k, transpose to As[k][m]
        #pragma unroll
        for (int i = 0; i < 2; ++i) {
            int idx = tid + i * 256;          // [0,512)
            int m  = idx >> 2;                // 0..127
            int k4 = (idx & 3) * 4;           // 0,4,8,12
            float4 a4 = *(const float4*)&ctx[(size_t)(b * NTOK + p0 + m) * CDIM + k0 + k4];
            As[k4 + 0][m] = a4.x;
            As[k4 + 1][m] = a4.y;
            As[k4 + 2][m] = a4.z;
            As[k4 + 3][m] = a4.w;
        }
        // B tile: 256 float4, 1/thread
        {
            int kk = tid >> 4;
            int n4 = (tid & 15) * 4;
            *(float4*)&Bs[kk][n4] = *(const float4*)&w[(size_t)(k0 + kk) * CDIM + n0 + n4];
        }
        __syncthreads();

        #pragma unroll
        for (int kk = 0; kk < 16; ++kk) {
            float4 a0 = *(const float4*)&As[kk][ty * 8];
            float4 a1 = *(const float4*)&As[kk][ty * 8 + 4];
            float4 b0 = *(const float4*)&Bs[kk][tx * 4];
            float a[8] = {a0.x, a0.y, a0.z, a0.w, a1.x, a1.y, a1.z, a1.w};
            float bb[4] = {b0.x, b0.y, b0.z, b0.w};
            #pragma unroll
            for (int i = 0; i < 8; ++i)
                #pragma unroll
                for (int j = 0; j < 4; ++j)
                    acc[i][j] = fmaf(a[i], bb[j], acc[i][j]);
        }
        __syncthreads();
    }

    // transpose through LDS, then coalesced store to out[b][c'][p]
    #pragma unroll
    for (int i = 0; i < 8; ++i)
        #pragma unroll
        for (int j = 0; j < 4; ++j)
            Tr[tx * 4 + j][ty * 8 + i] = acc[i][j];
    __syncthreads();

    #pragma unroll
    for (int i = 0; i < 8; ++i) {
        int idx = tid + i * 256;              // [0,2048) float4s
        int row = idx >> 5;                   // 0..63 (c' local)
        int p4  = (idx & 31) * 4;             // 0..124
        float4 val = *(const float4*)&Tr[row][p4];
        *(float4*)&out[((size_t)b * CDIM + n0 + row) * NTOK + p0 + p4] = val;
    }
}

// ---------------------------------------------------------------------------
extern "C" void kernel_launch(void* const* d_in, const int* in_sizes, int n_in,
                              void* d_out, int out_size, void* d_ws, size_t ws_size,
                              hipStream_t stream) {
    (void)in_sizes; (void)n_in; (void)out_size; (void)ws_size;
    const float* x      = (const float*)d_in[0];
    const float* w_qkv  = (const float*)d_in[1];
    const float* w_proj = (const float*)d_in[2];
    float* out = (float*)d_out;

    float* ws  = (float*)d_ws;
    float* b2  = ws;                                   // 768*2304       = 1,769,472
    float* q   = b2 + (size_t)CDIM * C3;               // 8*12*1024*64   = 6,291,456
    float* k   = q  + (size_t)NB * NHEAD * NTOK * DHEAD;
    float* v   = k  + (size_t)NB * NHEAD * NTOK * DHEAD;
    float* ctx = v  + (size_t)NB * NHEAD * NTOK * DHEAD;  // 8*1024*768

    // 0) repack weights
    repack_w<<<(CDIM * C3 + 255) / 256, 256, 0, stream>>>(w_qkv, b2);
    // 1) QKV GEMM
    qkv_gemm<<<dim3(64, 18), 256, 0, stream>>>(x, b2, q, k, v);
    // 2) attention
    attn_kernel<<<dim3(16, 96), 256, 0, stream>>>(q, k, v, ctx);
    // 3) projection + output transpose
    proj_gemm<<<dim3(64, 12), 256, 0, stream>>>(ctx, w_proj, out);
}

// Round 2
// 762.930 us; speedup vs baseline: 1.5213x; 1.5213x over previous
//
#include <hip/hip_runtime.h>

// Problem constants
#define NB    8      // batch
#define CDIM  768    // channels
#define NTOK  1024   // tokens = 32*32
#define NHEAD 12
#define DHEAD 64
#define C3    2304   // 3*CDIM

typedef short  s8v __attribute__((ext_vector_type(8)));
typedef float  f4v __attribute__((ext_vector_type(4)));

#define MFMA16(a, b, c) __builtin_amdgcn_mfma_f32_16x16x32_bf16((a), (b), (c), 0, 0, 0)

// fp32 -> bf16 round-to-nearest-even (bit trick, no NaN inputs here)
static __device__ __forceinline__ unsigned short f2bf(float f) {
    unsigned u = __float_as_uint(f);
    u += 0x7fffu + ((u >> 16) & 1u);
    return (unsigned short)(u >> 16);
}
static __device__ __forceinline__ float bf2f(unsigned short b) {
    return __uint_as_float(((unsigned)b) << 16);
}
// split x into hi/lo bf16, packed as u32: lo<<16 | hi
static __device__ __forceinline__ unsigned packsplit(float x) {
    unsigned short h = f2bf(x);
    unsigned short l = f2bf(x - bf2f(h));
    return (unsigned)h | ((unsigned)l << 16);
}
// 8 packed words -> hi/lo bf16x8 fragments
static __device__ __forceinline__ void unpack8(uint4 a, uint4 b, s8v& h, s8v& l) {
    unsigned x0 = a.x, x1 = a.y, x2 = a.z, x3 = a.w;
    unsigned x4 = b.x, x5 = b.y, x6 = b.z, x7 = b.w;
    h = (s8v){(short)x0, (short)x1, (short)x2, (short)x3,
              (short)x4, (short)x5, (short)x6, (short)x7};
    l = (s8v){(short)(x0 >> 16), (short)(x1 >> 16), (short)(x2 >> 16), (short)(x3 >> 16),
              (short)(x4 >> 16), (short)(x5 >> 16), (short)(x6 >> 16), (short)(x7 >> 16)};
}

// ---------------------------------------------------------------------------
// Kernel 0: repack w_qkv[c][d*36 + t*12 + h] -> B2[c][th*64 + d]
// ---------------------------------------------------------------------------
__global__ void repack_w(const float* __restrict__ w, float* __restrict__ b2) {
    int g = blockIdx.x * 256 + threadIdx.x;
    if (g >= CDIM * C3) return;
    int c = g / C3;
    int r = g - c * C3;
    int th = r >> 6;
    int d  = r & 63;
    b2[g] = w[c * C3 + d * 36 + th];
}

// ---------------------------------------------------------------------------
// Kernel 1: QKV GEMM (fp32 VALU, unchanged from R1 — known-good).
// ---------------------------------------------------------------------------
__launch_bounds__(256)
__global__ void qkv_gemm(const float* __restrict__ x, const float* __restrict__ b2,
                         float* __restrict__ q, float* __restrict__ k,
                         float* __restrict__ v) {
    __shared__ float As[16][128];
    __shared__ float Bs[16][128];

    const int tid = threadIdx.x;
    const int tx = tid & 15, ty = tid >> 4;
    const int m0 = blockIdx.x * 128;
    const int n0 = blockIdx.y * 128;
    const int b  = m0 >> 10;
    const int p0 = m0 & 1023;

    const float* xb = x + (size_t)b * CDIM * NTOK;

    float acc[8][8] = {};

    for (int k0 = 0; k0 < CDIM; k0 += 16) {
        #pragma unroll
        for (int i = 0; i < 2; ++i) {
            int idx = tid + i * 256;
            int kk = idx >> 5;
            int c4 = (idx & 31) * 4;
            float4 av = *(const float4*)&xb[(size_t)(k0 + kk) * NTOK + p0 + c4];
            *(float4*)&As[kk][c4] = av;
            float4 bv = *(const float4*)&b2[(size_t)(k0 + kk) * C3 + n0 + c4];
            *(float4*)&Bs[kk][c4] = bv;
        }
        __syncthreads();

        #pragma unroll
        for (int kk = 0; kk < 16; ++kk) {
            float4 a0 = *(const float4*)&As[kk][ty * 8];
            float4 a1 = *(const float4*)&As[kk][ty * 8 + 4];
            float4 b0 = *(const float4*)&Bs[kk][tx * 8];
            float4 b1 = *(const float4*)&Bs[kk][tx * 8 + 4];
            float a[8] = {a0.x, a0.y, a0.z, a0.w, a1.x, a1.y, a1.z, a1.w};
            float bb[8] = {b0.x, b0.y, b0.z, b0.w, b1.x, b1.y, b1.z, b1.w};
            #pragma unroll
            for (int i = 0; i < 8; ++i)
                #pragma unroll
                for (int j = 0; j < 8; ++j)
                    acc[i][j] = fmaf(a[i], bb[j], acc[i][j]);
        }
        __syncthreads();
    }

    const int np = n0 + tx * 8;
    const int th = np >> 6;
    const int db = np & 63;
    const int t  = th / 12;
    const int h  = th - t * 12;
    float* dst = (t == 0 ? q : (t == 1 ? k : v)) + ((size_t)(b * 12 + h) * NTOK) * DHEAD;
    #pragma unroll
    for (int i = 0; i < 8; ++i) {
        int p = p0 + ty * 8 + i;
        *(float4*)&dst[(size_t)p * DHEAD + db] =
            make_float4(acc[i][0], acc[i][1], acc[i][2], acc[i][3]);
        *(float4*)&dst[(size_t)p * DHEAD + db + 4] =
            make_float4(acc[i][4], acc[i][5], acc[i][6], acc[i][7]);
    }
}

// ---------------------------------------------------------------------------
// Kernel 2: MFMA flash attention, bf16x3 split precision.
// Block = 256 thr = 4 waves; QBLK = 128 (wave owns 2 x 16-row tiles);
// KVBLK = 64; D = 64.  energy = (q*8).k  (reference MULTIPLIES by 8).
//
// LDS arrays hold u32 words = (bf16_lo << 16) | bf16_hi, row stride 68 words
// (272 B, 16B-aligned).  Fragment reads hit bank (4*(l&15)+8*(l>>4))%32 ->
// 8 lanes per 4-bank group, 8 words/bank per b128 pair = conflict-free peak.
//
// mfma_f32_16x16x32_bf16 layouts (m89-verified):
//   A: lane holds A[row=l&15][k=(l>>4)*8+j]
//   B: lane holds B[k=(l>>4)*8+j][col=l&15]
//   C/D: lane holds D[row=(l>>4)*4+reg][col=l&15]
// ---------------------------------------------------------------------------
__launch_bounds__(256)
__global__ void attn_mfma(const float* __restrict__ q, const float* __restrict__ k,
                          const float* __restrict__ v, float* __restrict__ ctx) {
    __shared__ unsigned K32[64][68];    // [kv][d]   packed hi/lo
    __shared__ unsigned Vt32[64][68];   // [d][kv]   packed hi/lo (transposed)
    __shared__ unsigned P32[128][68];   // [q_local][kv] packed hi/lo, wave-private rows

    const int tid = threadIdx.x;
    const int l  = tid & 63;
    const int w  = tid >> 6;        // wave 0..3
    const int lm = l & 15;
    const int lg = l >> 4;
    const int bh = blockIdx.y;      // 0..95
    const int p0 = blockIdx.x * 128;

    const float* Qb = q + (size_t)bh * NTOK * DHEAD;
    const float* Kb = k + (size_t)bh * NTOK * DHEAD;
    const float* Vb = v + (size_t)bh * NTOK * DHEAD;

    // ---- Q fragments (held in registers for the whole kernel), pre-scaled x8
    s8v qh[2][2], ql[2][2];
    #pragma unroll
    for (int t = 0; t < 2; ++t)
        #pragma unroll
        for (int kk = 0; kk < 2; ++kk) {
            const float* src = Qb + (size_t)(p0 + w * 32 + t * 16 + lm) * DHEAD + kk * 32 + lg * 8;
            float4 a = *(const float4*)src;
            float4 b = *(const float4*)(src + 4);
            float vals[8] = {a.x, a.y, a.z, a.w, b.x, b.y, b.z, b.w};
            s8v hh, ll;
            #pragma unroll
            for (int j = 0; j < 8; ++j) {
                float xv = vals[j] * 8.0f;
                unsigned short hb = f2bf(xv);
                hh[j] = (short)hb;
                ll[j] = (short)f2bf(xv - bf2f(hb));
            }
            qh[t][kk] = hh; ql[t][kk] = ll;
        }

    f4v o[2][4];
    float mrun[2][4], lrun[2][4];
    #pragma unroll
    for (int t = 0; t < 2; ++t)
        #pragma unroll
        for (int c = 0; c < 4; ++c)
            o[t][c] = (f4v){0.f, 0.f, 0.f, 0.f};
    #pragma unroll
    for (int t = 0; t < 2; ++t)
        #pragma unroll
        for (int i = 0; i < 4; ++i) { mrun[t][i] = -3.0e38f; lrun[t][i] = 0.f; }

    const int sr = tid >> 2;    // staging row 0..63
    const int sg = tid & 3;     // staging 16-float segment 0..3

    for (int kt = 0; kt < 16; ++kt) {
        __syncthreads();    // all waves done reading K32/Vt32 of previous tile

        // ---- stage K and V~T (fp32 -> split bf16 packed u32)
        {
            const float* ksrc = Kb + (size_t)(kt * 64 + sr) * DHEAD + sg * 16;
            const float* vsrc = Vb + (size_t)(kt * 64 + sr) * DHEAD + sg * 16;
            #pragma unroll
            for (int jj = 0; jj < 4; ++jj) {
                float4 kf = *(const float4*)(ksrc + jj * 4);
                uint4 pw;
                pw.x = packsplit(kf.x); pw.y = packsplit(kf.y);
                pw.z = packsplit(kf.z); pw.w = packsplit(kf.w);
                *(uint4*)&K32[sr][sg * 16 + jj * 4] = pw;
            }
            #pragma unroll
            for (int jj = 0; jj < 4; ++jj) {
                float4 vf = *(const float4*)(vsrc + jj * 4);
                int d0 = sg * 16 + jj * 4;
                Vt32[d0 + 0][sr] = packsplit(vf.x);
                Vt32[d0 + 1][sr] = packsplit(vf.y);
                Vt32[d0 + 2][sr] = packsplit(vf.z);
                Vt32[d0 + 3][sr] = packsplit(vf.w);
            }
        }
        __syncthreads();

        // ---- S = Q.K^T  (bf16x3: qh*kh + qh*kl + ql*kh)
        f4v sa[2][4];
        #pragma unroll
        for (int t = 0; t < 2; ++t)
            #pragma unroll
            for (int c = 0; c < 4; ++c)
                sa[t][c] = (f4v){0.f, 0.f, 0.f, 0.f};

        #pragma unroll
        for (int kk = 0; kk < 2; ++kk)
            #pragma unroll
            for (int c = 0; c < 4; ++c) {
                uint4 a0 = *(const uint4*)&K32[c * 16 + lm][kk * 32 + lg * 8];
                uint4 a1 = *(const uint4*)&K32[c * 16 + lm][kk * 32 + lg * 8 + 4];
                s8v kh, kl;
                unpack8(a0, a1, kh, kl);
                #pragma unroll
                for (int t = 0; t < 2; ++t) {
                    sa[t][c] = MFMA16(qh[t][kk], kh, sa[t][c]);
                    sa[t][c] = MFMA16(qh[t][kk], kl, sa[t][c]);
                    sa[t][c] = MFMA16(ql[t][kk], kh, sa[t][c]);
                }
            }

        // ---- online softmax (rows live in 16-lane groups; width-16 xor reduce)
        #pragma unroll
        for (int t = 0; t < 2; ++t) {
            float f_[4];
            #pragma unroll
            for (int i = 0; i < 4; ++i) {
                float mt = fmaxf(fmaxf(sa[t][0][i], sa[t][1][i]),
                                 fmaxf(sa[t][2][i], sa[t][3][i]));
                #pragma unroll
                for (int off = 1; off < 16; off <<= 1)
                    mt = fmaxf(mt, __shfl_xor(mt, off, 16));
                float mn = fmaxf(mrun[t][i], mt);
                f_[i] = __expf(mrun[t][i] - mn);
                mrun[t][i] = mn;
            }
            #pragma unroll
            for (int i = 0; i < 4; ++i) {
                float pv[4];
                float rs = 0.f;
                #pragma unroll
                for (int c = 0; c < 4; ++c) {
                    pv[c] = __expf(sa[t][c][i] - mrun[t][i]);
                    rs += pv[c];
                }
                #pragma unroll
                for (int off = 1; off < 16; off <<= 1)
                    rs += __shfl_xor(rs, off, 16);
                lrun[t][i] = lrun[t][i] * f_[i] + rs;
                #pragma unroll
                for (int c = 0; c < 4; ++c)
                    o[t][c][i] *= f_[i];
                #pragma unroll
                for (int c = 0; c < 4; ++c)
                    P32[w * 32 + t * 16 + lg * 4 + i][c * 16 + lm] = packsplit(pv[c]);
            }
        }

        // ---- O += P.V  (wave-private P rows: no barrier needed, lgkmcnt only)
        s8v ph[2][2], pl[2][2];
        #pragma unroll
        for (int t = 0; t < 2; ++t)
            #pragma unroll
            for (int kk = 0; kk < 2; ++kk) {
                uint4 a0 = *(const uint4*)&P32[w * 32 + t * 16 + lm][kk * 32 + lg * 8];
                uint4 a1 = *(const uint4*)&P32[w * 32 + t * 16 + lm][kk * 32 + lg * 8 + 4];
                unpack8(a0, a1, ph[t][kk], pl[t][kk]);
            }
        #pragma unroll
        for (int c = 0; c < 4; ++c)
            #pragma unroll
            for (int kk = 0; kk < 2; ++kk) {
                uint4 b0 = *(const uint4*)&Vt32[c * 16 + lm][kk * 32 + lg * 8];
                uint4 b1 = *(const uint4*)&Vt32[c * 16 + lm][kk * 32 + lg * 8 + 4];
                s8v vh, vl;
                unpack8(b0, b1, vh, vl);
                #pragma unroll
                for (int t = 0; t < 2; ++t) {
                    o[t][c] = MFMA16(ph[t][kk], vh, o[t][c]);
                    o[t][c] = MFMA16(ph[t][kk], vl, o[t][c]);
                    o[t][c] = MFMA16(pl[t][kk], vh, o[t][c]);
                }
            }
    }

    // ---- epilogue: ctx[b][p][h*64+d] = O / l
    const int b  = bh / NHEAD;
    const int hh = bh - b * NHEAD;
    #pragma unroll
    for (int t = 0; t < 2; ++t)
        #pragma unroll
        for (int i = 0; i < 4; ++i) {
            float inv = 1.f / lrun[t][i];
            int p = p0 + w * 32 + t * 16 + lg * 4 + i;
            float* dst = ctx + ((size_t)(b * NTOK + p)) * CDIM + hh * DHEAD;
            #pragma unroll
            for (int c = 0; c < 4; ++c)
                dst[c * 16 + lm] = o[t][c][i] * inv;
        }
}

// ---------------------------------------------------------------------------
// Kernel 3: proj GEMM (fp32 VALU, unchanged from R1 — known-good).
// ---------------------------------------------------------------------------
__launch_bounds__(256)
__global__ void proj_gemm(const float* __restrict__ ctx, const float* __restrict__ w,
                          float* __restrict__ out) {
    __shared__ float As[16][132];
    __shared__ float Bs[16][64];
    __shared__ float Tr[64][132];

    const int tid = threadIdx.x;
    const int tx = tid & 15, ty = tid >> 4;
    const int m0 = blockIdx.x * 128;
    const int n0 = blockIdx.y * 64;
    const int b  = m0 >> 10;
    const int p0 = m0 & 1023;

    float acc[8][4] = {};

    for (int k0 = 0; k0 < CDIM; k0 += 16) {
        #pragma unroll
        for (int i = 0; i < 2; ++i) {
            int idx = tid + i * 256;
            int m  = idx >> 2;
            int k4 = (idx & 3) * 4;
            float4 a4 = *(const float4*)&ctx[(size_t)(b * NTOK + p0 + m) * CDIM + k0 + k4];
            As[k4 + 0][m] = a4.x;
            As[k4 + 1][m] = a4.y;
            As[k4 + 2][m] = a4.z;
            As[k4 + 3][m] = a4.w;
        }
        {
            int kk = tid >> 4;
            int n4 = (tid & 15) * 4;
            *(float4*)&Bs[kk][n4] = *(const float4*)&w[(size_t)(k0 + kk) * CDIM + n0 + n4];
        }
        __syncthreads();

        #pragma unroll
        for (int kk = 0; kk < 16; ++kk) {
            float4 a0 = *(const float4*)&As[kk][ty * 8];
            float4 a1 = *(const float4*)&As[kk][ty * 8 + 4];
            float4 b0 = *(const float4*)&Bs[kk][tx * 4];
            float a[8] = {a0.x, a0.y, a0.z, a0.w, a1.x, a1.y, a1.z, a1.w};
            float bb[4] = {b0.x, b0.y, b0.z, b0.w};
            #pragma unroll
            for (int i = 0; i < 8; ++i)
                #pragma unroll
                for (int j = 0; j < 4; ++j)
                    acc[i][j] = fmaf(a[i], bb[j], acc[i][j]);
        }
        __syncthreads();
    }

    #pragma unroll
    for (int i = 0; i < 8; ++i)
        #pragma unroll
        for (int j = 0; j < 4; ++j)
            Tr[tx * 4 + j][ty * 8 + i] = acc[i][j];
    __syncthreads();

    #pragma unroll
    for (int i = 0; i < 8; ++i) {
        int idx = tid + i * 256;
        int row = idx >> 5;
        int p4  = (idx & 31) * 4;
        float4 val = *(const float4*)&Tr[row][p4];
        *(float4*)&out[((size_t)b * CDIM + n0 + row) * NTOK + p0 + p4] = val;
    }
}

// ---------------------------------------------------------------------------
extern "C" void kernel_launch(void* const* d_in, const int* in_sizes, int n_in,
                              void* d_out, int out_size, void* d_ws, size_t ws_size,
                              hipStream_t stream) {
    (void)in_sizes; (void)n_in; (void)out_size; (void)ws_size;
    const float* x      = (const float*)d_in[0];
    const float* w_qkv  = (const float*)d_in[1];
    const float* w_proj = (const float*)d_in[2];
    float* out = (float*)d_out;

    float* ws  = (float*)d_ws;
    float* b2  = ws;
    float* q   = b2 + (size_t)CDIM * C3;
    float* k   = q  + (size_t)NB * NHEAD * NTOK * DHEAD;
    float* v   = k  + (size_t)NB * NHEAD * NTOK * DHEAD;
    float* ctx = v  + (size_t)NB * NHEAD * NTOK * DHEAD;

    repack_w<<<(CDIM * C3 + 255) / 256, 256, 0, stream>>>(w_qkv, b2);
    qkv_gemm<<<dim3(64, 18), 256, 0, stream>>>(x, b2, q, k, v);
    attn_mfma<<<dim3(8, 96), 256, 0, stream>>>(q, k, v, ctx);
    proj_gemm<<<dim3(64, 12), 256, 0, stream>>>(ctx, w_proj, out);
}

// Round 3
// 500.898 us; speedup vs baseline: 2.3172x; 1.5231x over previous
//
#include <hip/hip_runtime.h>

// Problem constants
#define NB    8      // batch
#define CDIM  768    // channels
#define NTOK  1024   // tokens = 32*32
#define NHEAD 12
#define DHEAD 64
#define C3    2304   // 3*CDIM

typedef short  s8v __attribute__((ext_vector_type(8)));
typedef float  f4v __attribute__((ext_vector_type(4)));

#define MFMA16(a, b, c) __builtin_amdgcn_mfma_f32_16x16x32_bf16((a), (b), (c), 0, 0, 0)

// fp32 -> bf16 round-to-nearest-even
static __device__ __forceinline__ unsigned short f2bf(float f) {
    unsigned u = __float_as_uint(f);
    u += 0x7fffu + ((u >> 16) & 1u);
    return (unsigned short)(u >> 16);
}
static __device__ __forceinline__ float bf2f(unsigned short b) {
    return __uint_as_float(((unsigned)b) << 16);
}
// split x into hi/lo bf16, packed as u32: lo<<16 | hi
static __device__ __forceinline__ unsigned packsplit(float x) {
    unsigned short h = f2bf(x);
    unsigned short l = f2bf(x - bf2f(h));
    return (unsigned)h | ((unsigned)l << 16);
}
// 8 packed words -> hi/lo bf16x8 fragments
static __device__ __forceinline__ void unpack8(uint4 a, uint4 b, s8v& h, s8v& l) {
    unsigned x0 = a.x, x1 = a.y, x2 = a.z, x3 = a.w;
    unsigned x4 = b.x, x5 = b.y, x6 = b.z, x7 = b.w;
    h = (s8v){(short)x0, (short)x1, (short)x2, (short)x3,
              (short)x4, (short)x5, (short)x6, (short)x7};
    l = (s8v){(short)(x0 >> 16), (short)(x1 >> 16), (short)(x2 >> 16), (short)(x3 >> 16),
              (short)(x4 >> 16), (short)(x5 >> 16), (short)(x6 >> 16), (short)(x7 >> 16)};
}

// async global->LDS, 16B per lane; lds dest is wave-uniform base + lane*16
static __device__ __forceinline__ void gload16(const unsigned short* gsrc,
                                               unsigned short* ldst) {
    __builtin_amdgcn_global_load_lds(
        (const __attribute__((address_space(1))) void*)gsrc,
        (__attribute__((address_space(3))) void*)ldst, 16, 0, 0);
}

// ---------------------------------------------------------------------------
// Kernel 0a: transpose+split x[b][c][p] (fp32) -> xt_h/xt_l [b][p][c] (bf16).
// 64x64 tiles through LDS; coalesced on both sides.
// ---------------------------------------------------------------------------
__launch_bounds__(256)
__global__ void split_x(const float* __restrict__ x,
                        unsigned short* __restrict__ xh,
                        unsigned short* __restrict__ xl) {
    __shared__ float Tf[64][65];
    const int t  = threadIdx.x;
    const int p0 = blockIdx.x * 64;
    const int c0 = blockIdx.y * 64;
    const int b  = blockIdx.z;

    #pragma unroll
    for (int i = 0; i < 4; ++i) {
        int cl = (t >> 4) + i * 16;
        int pl = (t & 15) * 4;
        float4 v4 = *(const float4*)&x[((size_t)(b * CDIM) + c0 + cl) * NTOK + p0 + pl];
        Tf[cl][pl + 0] = v4.x; Tf[cl][pl + 1] = v4.y;
        Tf[cl][pl + 2] = v4.z; Tf[cl][pl + 3] = v4.w;
    }
    __syncthreads();
    #pragma unroll
    for (int i = 0; i < 4; ++i) {
        int pr = (t >> 4) + i * 16;
        int c4 = (t & 15) * 4;
        unsigned short hs[4], ls[4];
        #pragma unroll
        for (int j = 0; j < 4; ++j) {
            float val = Tf[c4 + j][pr];
            hs[j] = f2bf(val);
            ls[j] = f2bf(val - bf2f(hs[j]));
        }
        size_t o = ((size_t)(b * NTOK) + p0 + pr) * CDIM + c0 + c4;
        *(ushort4*)&xh[o] = make_ushort4(hs[0], hs[1], hs[2], hs[3]);
        *(ushort4*)&xl[o] = make_ushort4(ls[0], ls[1], ls[2], ls[3]);
    }
}

// ---------------------------------------------------------------------------
// Kernel 0b: repack+transpose+split w_qkv[c][d*36+t*12+h] ->
//            wqt_h/wqt_l [n'=(t*12+h)*64+d][c]  (bf16, K-innermost).
// Block handles 16 c-rows x 144 n-cols (= 4 d-values x all 36 th).
// ---------------------------------------------------------------------------
__launch_bounds__(256)
__global__ void split_w(const float* __restrict__ w,
                        unsigned short* __restrict__ wh,
                        unsigned short* __restrict__ wl) {
    __shared__ float Wf[16][148];
    const int t  = threadIdx.x;
    const int d0 = blockIdx.x * 4;           // n-tile base = d0*36
    const int c0 = blockIdx.y * 16;

    #pragma unroll
    for (int i = 0; i < 9; ++i) {
        int idx = t + i * 256;               // [0,2304)
        int cl = idx / 144;
        int nl = idx - cl * 144;
        Wf[cl][nl] = w[(size_t)(c0 + cl) * C3 + d0 * 36 + nl];
    }
    __syncthreads();
    #pragma unroll
    for (int i = 0; i < 9; ++i) {
        int idx = t + i * 256;
        int r  = idx >> 4;                   // 0..143 output-row local
        int cc = idx & 15;
        int dd = r / 36;
        int th = r - dd * 36;
        float val = Wf[cc][dd * 36 + th];
        unsigned short hb = f2bf(val);
        size_t o = ((size_t)(th * 64 + d0 + dd)) * CDIM + c0 + cc;
        wh[o] = hb;
        wl[o] = f2bf(val - bf2f(hb));
    }
}

// ---------------------------------------------------------------------------
// Kernel 1: QKV GEMM, bf16x3 MFMA.  M=8192 (b,p), N=2304 (th,d), K=768.
// 128x128 tile, BK=32, 4 waves (2x2 quadrants of 64x64), 4x4 frags each.
// Staging: global_load_lds 16B from pre-split bf16 arrays into linear LDS.
// Output: Q/K/V packed hi|lo u32, [bh][p][d]; Q pre-scaled by 8 (=sqrt(64)).
// ---------------------------------------------------------------------------
__launch_bounds__(256)
__global__ void qkv_mfma(const unsigned short* __restrict__ xh,
                         const unsigned short* __restrict__ xl,
                         const unsigned short* __restrict__ wh,
                         const unsigned short* __restrict__ wl,
                         unsigned* __restrict__ Qp, unsigned* __restrict__ Kp,
                         unsigned* __restrict__ Vp) {
    __shared__ unsigned short Ah[128][32];
    __shared__ unsigned short Al[128][32];
    __shared__ unsigned short Bh[128][32];
    __shared__ unsigned short Bl[128][32];

    const int tid = threadIdx.x;
    const int l   = tid & 63;
    const int w   = tid >> 6;
    const int lm  = l & 15;
    const int lg  = l >> 4;
    const int wr  = w >> 1;           // wave row quadrant
    const int wc  = w & 1;            // wave col quadrant
    const int m0  = blockIdx.x * 128;
    const int n0  = blockIdx.y * 128;
    const int b   = m0 >> 10;
    const int p0  = m0 & 1023;

    const size_t xbase = ((size_t)(b * NTOK) + p0) * CDIM;   // row-major [m][768]
    const int lrow = l >> 2;          // 0..15 within chunk
    const int kq   = (l & 3) * 8;     // 8-elem k segment

    f4v acc[4][4];
    #pragma unroll
    for (int i = 0; i < 4; ++i)
        #pragma unroll
        for (int j = 0; j < 4; ++j)
            acc[i][j] = (f4v){0.f, 0.f, 0.f, 0.f};

    for (int k0 = 0; k0 < CDIM; k0 += 32) {
        // stage 4 arrays x 8KB via global_load_lds (wave chunks of 1KB)
        #pragma unroll
        for (int i = 0; i < 2; ++i) {
            int ch = w * 2 + i;               // chunk 0..7
            int m  = ch * 16 + lrow;          // tile row 0..127
            int lo = ch * 512;                // ushort offset of chunk in LDS
            gload16(xh + xbase + (size_t)m * CDIM + k0 + kq, &Ah[0][0] + lo);
            gload16(xl + xbase + (size_t)m * CDIM + k0 + kq, &Al[0][0] + lo);
            gload16(wh + (size_t)(n0 + m) * CDIM + k0 + kq,  &Bh[0][0] + lo);
            gload16(wl + (size_t)(n0 + m) * CDIM + k0 + kq,  &Bl[0][0] + lo);
        }
        __syncthreads();

        s8v ah[4], al[4], bh[4], bl[4];
        #pragma unroll
        for (int mi = 0; mi < 4; ++mi) {
            int row = wr * 64 + mi * 16 + lm;
            ah[mi] = *(const s8v*)&Ah[row][lg * 8];
            al[mi] = *(const s8v*)&Al[row][lg * 8];
        }
        #pragma unroll
        for (int ni = 0; ni < 4; ++ni) {
            int row = wc * 64 + ni * 16 + lm;
            bh[ni] = *(const s8v*)&Bh[row][lg * 8];
            bl[ni] = *(const s8v*)&Bl[row][lg * 8];
        }
        #pragma unroll
        for (int mi = 0; mi < 4; ++mi)
            #pragma unroll
            for (int ni = 0; ni < 4; ++ni) {
                acc[mi][ni] = MFMA16(ah[mi], bh[ni], acc[mi][ni]);
                acc[mi][ni] = MFMA16(ah[mi], bl[ni], acc[mi][ni]);
                acc[mi][ni] = MFMA16(al[mi], bh[ni], acc[mi][ni]);
            }
        __syncthreads();
    }

    // epilogue: pack to u32 hi|lo, store to Q/K/V [bh][p][d]
    const int th = (n0 >> 6) + wc;    // (n0 + wc*64)/64, 0..35
    const int t3 = th / 12;
    const int h  = th - t3 * 12;
    const float scale = (t3 == 0) ? 8.0f : 1.0f;
    unsigned* dst = (t3 == 0 ? Qp : (t3 == 1 ? Kp : Vp)) +
                    (size_t)(b * NHEAD + h) * NTOK * DHEAD;
    #pragma unroll
    for (int mi = 0; mi < 4; ++mi)
        #pragma unroll
        for (int r = 0; r < 4; ++r) {
            int p = p0 + wr * 64 + mi * 16 + lg * 4 + r;
            #pragma unroll
            for (int ni = 0; ni < 4; ++ni)
                dst[(size_t)p * DHEAD + ni * 16 + lm] = packsplit(acc[mi][ni][r] * scale);
        }
}

// ---------------------------------------------------------------------------
// Kernel 2: MFMA flash attention, bf16x3.  Inputs are PACKED u32 (hi|lo bf16),
// Q pre-scaled by 8.  Block = 4 waves, QBLK=128, KVBLK=64.
// ---------------------------------------------------------------------------
__launch_bounds__(256)
__global__ void attn_mfma(const unsigned* __restrict__ Qp, const unsigned* __restrict__ Kp,
                          const unsigned* __restrict__ Vp, float* __restrict__ ctx) {
    __shared__ unsigned K32[64][68];    // [kv][d]
    __shared__ unsigned Vt32[64][68];   // [d][kv]
    __shared__ unsigned P32[128][68];   // [q_local][kv], wave-private rows

    const int tid = threadIdx.x;
    const int l  = tid & 63;
    const int w  = tid >> 6;
    const int lm = l & 15;
    const int lg = l >> 4;
    const int bh = blockIdx.y;
    const int p0 = blockIdx.x * 128;

    const unsigned* Qb = Qp + (size_t)bh * NTOK * DHEAD;
    const unsigned* Kb = Kp + (size_t)bh * NTOK * DHEAD;
    const unsigned* Vb = Vp + (size_t)bh * NTOK * DHEAD;

    // Q fragments (already scaled by 8, packed)
    s8v qh[2][2], ql[2][2];
    #pragma unroll
    for (int t = 0; t < 2; ++t)
        #pragma unroll
        for (int kk = 0; kk < 2; ++kk) {
            const unsigned* src = Qb + (size_t)(p0 + w * 32 + t * 16 + lm) * DHEAD + kk * 32 + lg * 8;
            uint4 a0 = *(const uint4*)src;
            uint4 a1 = *(const uint4*)(src + 4);
            unpack8(a0, a1, qh[t][kk], ql[t][kk]);
        }

    f4v o[2][4];
    float mrun[2][4], lrun[2][4];
    #pragma unroll
    for (int t = 0; t < 2; ++t)
        #pragma unroll
        for (int c = 0; c < 4; ++c)
            o[t][c] = (f4v){0.f, 0.f, 0.f, 0.f};
    #pragma unroll
    for (int t = 0; t < 2; ++t)
        #pragma unroll
        for (int i = 0; i < 4; ++i) { mrun[t][i] = -3.0e38f; lrun[t][i] = 0.f; }

    const int sr = tid >> 2;
    const int sg = tid & 3;

    for (int kt = 0; kt < 16; ++kt) {
        __syncthreads();

        // stage K and V^T (plain packed copies)
        {
            const unsigned* ksrc = Kb + (size_t)(kt * 64 + sr) * DHEAD + sg * 16;
            const unsigned* vsrc = Vb + (size_t)(kt * 64 + sr) * DHEAD + sg * 16;
            #pragma unroll
            for (int jj = 0; jj < 4; ++jj)
                *(uint4*)&K32[sr][sg * 16 + jj * 4] = *(const uint4*)(ksrc + jj * 4);
            #pragma unroll
            for (int jj = 0; jj < 4; ++jj) {
                uint4 vf = *(const uint4*)(vsrc + jj * 4);
                int d0 = sg * 16 + jj * 4;
                Vt32[d0 + 0][sr] = vf.x;
                Vt32[d0 + 1][sr] = vf.y;
                Vt32[d0 + 2][sr] = vf.z;
                Vt32[d0 + 3][sr] = vf.w;
            }
        }
        __syncthreads();

        // S = Q.K^T (bf16x3)
        f4v sa[2][4];
        #pragma unroll
        for (int t = 0; t < 2; ++t)
            #pragma unroll
            for (int c = 0; c < 4; ++c)
                sa[t][c] = (f4v){0.f, 0.f, 0.f, 0.f};

        #pragma unroll
        for (int kk = 0; kk < 2; ++kk)
            #pragma unroll
            for (int c = 0; c < 4; ++c) {
                uint4 a0 = *(const uint4*)&K32[c * 16 + lm][kk * 32 + lg * 8];
                uint4 a1 = *(const uint4*)&K32[c * 16 + lm][kk * 32 + lg * 8 + 4];
                s8v kh, kl;
                unpack8(a0, a1, kh, kl);
                #pragma unroll
                for (int t = 0; t < 2; ++t) {
                    sa[t][c] = MFMA16(qh[t][kk], kh, sa[t][c]);
                    sa[t][c] = MFMA16(qh[t][kk], kl, sa[t][c]);
                    sa[t][c] = MFMA16(ql[t][kk], kh, sa[t][c]);
                }
            }

        // online softmax
        #pragma unroll
        for (int t = 0; t < 2; ++t) {
            float f_[4];
            #pragma unroll
            for (int i = 0; i < 4; ++i) {
                float mt = fmaxf(fmaxf(sa[t][0][i], sa[t][1][i]),
                                 fmaxf(sa[t][2][i], sa[t][3][i]));
                #pragma unroll
                for (int off = 1; off < 16; off <<= 1)
                    mt = fmaxf(mt, __shfl_xor(mt, off, 16));
                float mn = fmaxf(mrun[t][i], mt);
                f_[i] = __expf(mrun[t][i] - mn);
                mrun[t][i] = mn;
            }
            #pragma unroll
            for (int i = 0; i < 4; ++i) {
                float pv[4];
                float rs = 0.f;
                #pragma unroll
                for (int c = 0; c < 4; ++c) {
                    pv[c] = __expf(sa[t][c][i] - mrun[t][i]);
                    rs += pv[c];
                }
                #pragma unroll
                for (int off = 1; off < 16; off <<= 1)
                    rs += __shfl_xor(rs, off, 16);
                lrun[t][i] = lrun[t][i] * f_[i] + rs;
                #pragma unroll
                for (int c = 0; c < 4; ++c)
                    o[t][c][i] *= f_[i];
                #pragma unroll
                for (int c = 0; c < 4; ++c)
                    P32[w * 32 + t * 16 + lg * 4 + i][c * 16 + lm] = packsplit(pv[c]);
            }
        }

        // O += P.V
        s8v ph[2][2], pl[2][2];
        #pragma unroll
        for (int t = 0; t < 2; ++t)
            #pragma unroll
            for (int kk = 0; kk < 2; ++kk) {
                uint4 a0 = *(const uint4*)&P32[w * 32 + t * 16 + lm][kk * 32 + lg * 8];
                uint4 a1 = *(const uint4*)&P32[w * 32 + t * 16 + lm][kk * 32 + lg * 8 + 4];
                unpack8(a0, a1, ph[t][kk], pl[t][kk]);
            }
        #pragma unroll
        for (int c = 0; c < 4; ++c)
            #pragma unroll
            for (int kk = 0; kk < 2; ++kk) {
                uint4 b0 = *(const uint4*)&Vt32[c * 16 + lm][kk * 32 + lg * 8];
                uint4 b1 = *(const uint4*)&Vt32[c * 16 + lm][kk * 32 + lg * 8 + 4];
                s8v vh, vl;
                unpack8(b0, b1, vh, vl);
                #pragma unroll
                for (int t = 0; t < 2; ++t) {
                    o[t][c] = MFMA16(ph[t][kk], vh, o[t][c]);
                    o[t][c] = MFMA16(ph[t][kk], vl, o[t][c]);
                    o[t][c] = MFMA16(pl[t][kk], vh, o[t][c]);
                }
            }
    }

    // epilogue
    const int b  = bh / NHEAD;
    const int hh = bh - b * NHEAD;
    #pragma unroll
    for (int t = 0; t < 2; ++t)
        #pragma unroll
        for (int i = 0; i < 4; ++i) {
            float inv = 1.f / lrun[t][i];
            int p = p0 + w * 32 + t * 16 + lg * 4 + i;
            float* dst = ctx + ((size_t)(b * NTOK + p)) * CDIM + hh * DHEAD;
            #pragma unroll
            for (int c = 0; c < 4; ++c)
                dst[c * 16 + lm] = o[t][c][i] * inv;
        }
}

// ---------------------------------------------------------------------------
// Kernel 3: proj GEMM (fp32 VALU, unchanged — known-good).
// ---------------------------------------------------------------------------
__launch_bounds__(256)
__global__ void proj_gemm(const float* __restrict__ ctx, const float* __restrict__ w,
                          float* __restrict__ out) {
    __shared__ float As[16][132];
    __shared__ float Bs[16][64];
    __shared__ float Tr[64][132];

    const int tid = threadIdx.x;
    const int tx = tid & 15, ty = tid >> 4;
    const int m0 = blockIdx.x * 128;
    const int n0 = blockIdx.y * 64;
    const int b  = m0 >> 10;
    const int p0 = m0 & 1023;

    float acc[8][4] = {};

    for (int k0 = 0; k0 < CDIM; k0 += 16) {
        #pragma unroll
        for (int i = 0; i < 2; ++i) {
            int idx = tid + i * 256;
            int m  = idx >> 2;
            int k4 = (idx & 3) * 4;
            float4 a4 = *(const float4*)&ctx[(size_t)(b * NTOK + p0 + m) * CDIM + k0 + k4];
            As[k4 + 0][m] = a4.x;
            As[k4 + 1][m] = a4.y;
            As[k4 + 2][m] = a4.z;
            As[k4 + 3][m] = a4.w;
        }
        {
            int kk = tid >> 4;
            int n4 = (tid & 15) * 4;
            *(float4*)&Bs[kk][n4] = *(const float4*)&w[(size_t)(k0 + kk) * CDIM + n0 + n4];
        }
        __syncthreads();

        #pragma unroll
        for (int kk = 0; kk < 16; ++kk) {
            float4 a0 = *(const float4*)&As[kk][ty * 8];
            float4 a1 = *(const float4*)&As[kk][ty * 8 + 4];
            float4 b0 = *(const float4*)&Bs[kk][tx * 4];
            float a[8] = {a0.x, a0.y, a0.z, a0.w, a1.x, a1.y, a1.z, a1.w};
            float bb[4] = {b0.x, b0.y, b0.z, b0.w};
            #pragma unroll
            for (int i = 0; i < 8; ++i)
                #pragma unroll
                for (int j = 0; j < 4; ++j)
                    acc[i][j] = fmaf(a[i], bb[j], acc[i][j]);
        }
        __syncthreads();
    }

    #pragma unroll
    for (int i = 0; i < 8; ++i)
        #pragma unroll
        for (int j = 0; j < 4; ++j)
            Tr[tx * 4 + j][ty * 8 + i] = acc[i][j];
    __syncthreads();

    #pragma unroll
    for (int i = 0; i < 8; ++i) {
        int idx = tid + i * 256;
        int row = idx >> 5;
        int p4  = (idx & 31) * 4;
        float4 val = *(const float4*)&Tr[row][p4];
        *(float4*)&out[((size_t)b * CDIM + n0 + row) * NTOK + p0 + p4] = val;
    }
}

// ---------------------------------------------------------------------------
extern "C" void kernel_launch(void* const* d_in, const int* in_sizes, int n_in,
                              void* d_out, int out_size, void* d_ws, size_t ws_size,
                              hipStream_t stream) {
    (void)in_sizes; (void)n_in; (void)out_size; (void)ws_size;
    const float* x      = (const float*)d_in[0];
    const float* w_qkv  = (const float*)d_in[1];
    const float* w_proj = (const float*)d_in[2];
    float* out = (float*)d_out;

    // workspace layout (ctx aliases xt — xt dead after qkv_mfma)
    const size_t QKV_ELEMS = (size_t)NB * NHEAD * NTOK * DHEAD;   // 6,291,456
    unsigned* Qp = (unsigned*)d_ws;
    unsigned* Kp = Qp + QKV_ELEMS;
    unsigned* Vp = Kp + QKV_ELEMS;
    unsigned short* xh = (unsigned short*)(Vp + QKV_ELEMS);
    unsigned short* xl = xh + (size_t)NB * NTOK * CDIM;
    float* ctx = (float*)xh;                                      // alias
    unsigned short* wh = (unsigned short*)(xl + (size_t)NB * NTOK * CDIM);
    unsigned short* wl = wh + (size_t)C3 * CDIM;

    split_x<<<dim3(16, 12, 8), 256, 0, stream>>>(x, xh, xl);
    split_w<<<dim3(16, 48), 256, 0, stream>>>(w_qkv, wh, wl);
    qkv_mfma<<<dim3(64, 18), 256, 0, stream>>>(xh, xl, wh, wl, Qp, Kp, Vp);
    attn_mfma<<<dim3(8, 96), 256, 0, stream>>>(Qp, Kp, Vp, ctx);
    proj_gemm<<<dim3(64, 12), 256, 0, stream>>>(ctx, w_proj, out);
}

// Round 5
// 367.718 us; speedup vs baseline: 3.1564x; 1.3622x over previous
//
#include <hip/hip_runtime.h>

#define NB    8
#define CDIM  768
#define NTOK  1024
#define NHEAD 12
#define DHEAD 64
#define C3    2304

typedef unsigned short u16;
typedef short  s8v __attribute__((ext_vector_type(8)));
typedef float  f4v __attribute__((ext_vector_type(4)));

#define MFMA16(a, b, c) __builtin_amdgcn_mfma_f32_16x16x32_bf16((a), (b), (c), 0, 0, 0)

static __device__ __forceinline__ u16 f2bf(float f) {
    unsigned u = __float_as_uint(f);
    u += 0x7fffu + ((u >> 16) & 1u);
    return (u16)(u >> 16);
}
static __device__ __forceinline__ float bf2f(u16 b) {
    return __uint_as_float(((unsigned)b) << 16);
}
static __device__ __forceinline__ unsigned packsplit(float x) {
    u16 h = f2bf(x);
    u16 l = f2bf(x - bf2f(h));
    return (unsigned)h | ((unsigned)l << 16);
}
static __device__ __forceinline__ void unpack8(uint4 a, uint4 b, s8v& h, s8v& l) {
    h = (s8v){(short)a.x, (short)a.y, (short)a.z, (short)a.w,
              (short)b.x, (short)b.y, (short)b.z, (short)b.w};
    l = (s8v){(short)(a.x >> 16), (short)(a.y >> 16), (short)(a.z >> 16), (short)(a.w >> 16),
              (short)(b.x >> 16), (short)(b.y >> 16), (short)(b.z >> 16), (short)(b.w >> 16)};
}
// SW32: swizzle for K-innermost bf16 arrays consumed as [row][32] BK=32 LDS tiles
// (64B rows, 4x 16B groups): group ^= (row>>1)&3  -> frag reads are 2-way (free).
static __device__ __forceinline__ int sw32i(int row, int k) {
    int g = (k >> 3) & 3;
    int gs = g ^ ((row >> 1) & 3);
    return (k & ~31) + (gs << 3) + (k & 7);
}
// async global->LDS 16B/lane: dst is WAVE-UNIFORM base (HW adds lane*16)
static __device__ __forceinline__ void gload16(const u16* gsrc, u16* ldst) {
    __builtin_amdgcn_global_load_lds(
        (const __attribute__((address_space(1))) void*)gsrc,
        (__attribute__((address_space(3))) void*)ldst, 16, 0, 0);
}

// ---------------------------------------------------------------------------
// 0a: x[b][c][p] fp32 -> xh/xl [b*p][c] bf16 split, SW32-swizzled by row m.
// ---------------------------------------------------------------------------
__launch_bounds__(256)
__global__ void split_x(const float* __restrict__ x,
                        u16* __restrict__ xh, u16* __restrict__ xl) {
    __shared__ float Tf[64][65];
    const int t  = threadIdx.x;
    const int p0 = blockIdx.x * 64;
    const int c0 = blockIdx.y * 64;
    const int b  = blockIdx.z;

    #pragma unroll
    for (int i = 0; i < 4; ++i) {
        int cl = (t >> 4) + i * 16;
        int pl = (t & 15) * 4;
        float4 v4 = *(const float4*)&x[((size_t)(b * CDIM) + c0 + cl) * NTOK + p0 + pl];
        Tf[cl][pl + 0] = v4.x; Tf[cl][pl + 1] = v4.y;
        Tf[cl][pl + 2] = v4.z; Tf[cl][pl + 3] = v4.w;
    }
    __syncthreads();
    #pragma unroll
    for (int i = 0; i < 4; ++i) {
        int pr = (t >> 4) + i * 16;
        int c4 = (t & 15) * 4;
        u16 hs[4], ls[4];
        #pragma unroll
        for (int j = 0; j < 4; ++j) {
            float val = Tf[c4 + j][pr];
            hs[j] = f2bf(val);
            ls[j] = f2bf(val - bf2f(hs[j]));
        }
        size_t m = (size_t)(b * NTOK) + p0 + pr;
        int ksw = sw32i(p0 + pr, c0 + c4);            // 4-run stays in one 8-group
        *(ushort4*)&xh[m * CDIM + ksw] = make_ushort4(hs[0], hs[1], hs[2], hs[3]);
        *(ushort4*)&xl[m * CDIM + ksw] = make_ushort4(ls[0], ls[1], ls[2], ls[3]);
    }
}

// ---------------------------------------------------------------------------
// 0b: w_qkv[c][d*36+t*12+h] -> wh/wl [n'=(t*12+h)*64+d][c], SW32-swizzled.
// ---------------------------------------------------------------------------
__launch_bounds__(256)
__global__ void split_w(const float* __restrict__ w,
                        u16* __restrict__ wh, u16* __restrict__ wl) {
    __shared__ float Wf[16][148];
    const int t  = threadIdx.x;
    const int d0 = blockIdx.x * 4;
    const int c0 = blockIdx.y * 16;

    #pragma unroll
    for (int i = 0; i < 9; ++i) {
        int idx = t + i * 256;
        int cl = idx / 144;
        int nl = idx - cl * 144;
        Wf[cl][nl] = w[(size_t)(c0 + cl) * C3 + d0 * 36 + nl];
    }
    __syncthreads();
    #pragma unroll
    for (int i = 0; i < 9; ++i) {
        int idx = t + i * 256;
        int r  = idx >> 4;
        int cc = idx & 15;
        int dd = r / 36;
        int th = r - dd * 36;
        float val = Wf[cc][dd * 36 + th];
        u16 hb = f2bf(val);
        int np = th * 64 + d0 + dd;
        size_t o = (size_t)np * CDIM + sw32i(np, c0 + cc);
        wh[o] = hb;
        wl[o] = f2bf(val - bf2f(hb));
    }
}

// ---------------------------------------------------------------------------
// 0c: w_proj[k][n] -> wph/wpl [n][k] bf16 split, SW32-swizzled by row n.
//     (launched AFTER qkv_mfma: wph/wpl alias the then-dead wh/wl region)
// ---------------------------------------------------------------------------
__launch_bounds__(256)
__global__ void split_wp(const float* __restrict__ w,
                         u16* __restrict__ wph, u16* __restrict__ wpl) {
    __shared__ float Tf[64][65];
    const int t  = threadIdx.x;
    const int n0 = blockIdx.x * 64;
    const int k0 = blockIdx.y * 64;

    #pragma unroll
    for (int i = 0; i < 4; ++i) {
        int kl = (t >> 4) + i * 16;
        int nl = (t & 15) * 4;
        float4 v4 = *(const float4*)&w[(size_t)(k0 + kl) * CDIM + n0 + nl];
        Tf[kl][nl + 0] = v4.x; Tf[kl][nl + 1] = v4.y;
        Tf[kl][nl + 2] = v4.z; Tf[kl][nl + 3] = v4.w;
    }
    __syncthreads();
    #pragma unroll
    for (int i = 0; i < 4; ++i) {
        int nr = (t >> 4) + i * 16;
        int k4 = (t & 15) * 4;
        u16 hs[4], ls[4];
        #pragma unroll
        for (int j = 0; j < 4; ++j) {
            float val = Tf[k4 + j][nr];
            hs[j] = f2bf(val);
            ls[j] = f2bf(val - bf2f(hs[j]));
        }
        int n = n0 + nr;
        int ksw = sw32i(n, k0 + k4);
        *(ushort4*)&wph[(size_t)n * CDIM + ksw] = make_ushort4(hs[0], hs[1], hs[2], hs[3]);
        *(ushort4*)&wpl[(size_t)n * CDIM + ksw] = make_ushort4(ls[0], ls[1], ls[2], ls[3]);
    }
}

// ---------------------------------------------------------------------------
// 1: QKV GEMM bf16x3 MFMA.  Outputs: Qp packed u32 (x8), Kh/Kl planar
//    SW64-swizzled [bh][p][d], Vh/Vl planar plain [bh][p][d].
// ---------------------------------------------------------------------------
__launch_bounds__(256)
__global__ void qkv_mfma(const u16* __restrict__ xh, const u16* __restrict__ xl,
                         const u16* __restrict__ wh, const u16* __restrict__ wl,
                         unsigned* __restrict__ Qp,
                         u16* __restrict__ Khg, u16* __restrict__ Klg,
                         u16* __restrict__ Vhg, u16* __restrict__ Vlg) {
    __shared__ u16 Ah[128][32];
    __shared__ u16 Al[128][32];
    __shared__ u16 Bh[128][32];
    __shared__ u16 Bl[128][32];

    const int tid = threadIdx.x;
    const int l   = tid & 63;
    const int w   = tid >> 6;
    const int lm  = l & 15;
    const int lg  = l >> 4;
    const int wr  = w >> 1;
    const int wc  = w & 1;
    const int m0  = blockIdx.x * 128;
    const int n0  = blockIdx.y * 128;
    const int b   = m0 >> 10;
    const int p0  = m0 & 1023;

    const size_t xbase = ((size_t)(b * NTOK) + p0) * CDIM;
    const int lrow = l >> 2;
    const int kq   = (l & 3) * 8;
    const int asw  = (lg ^ ((lm >> 1) & 3)) * 8;   // SW32 fragment offset

    f4v acc[4][4];
    #pragma unroll
    for (int i = 0; i < 4; ++i)
        #pragma unroll
        for (int j = 0; j < 4; ++j)
            acc[i][j] = (f4v){0.f, 0.f, 0.f, 0.f};

    for (int k0 = 0; k0 < CDIM; k0 += 32) {
        #pragma unroll
        for (int i = 0; i < 2; ++i) {
            int ch = w * 2 + i;
            int m  = ch * 16 + lrow;
            int lo = ch * 512;
            gload16(xh + xbase + (size_t)m * CDIM + k0 + kq, &Ah[0][0] + lo);
            gload16(xl + xbase + (size_t)m * CDIM + k0 + kq, &Al[0][0] + lo);
            gload16(wh + (size_t)(n0 + m) * CDIM + k0 + kq,  &Bh[0][0] + lo);
            gload16(wl + (size_t)(n0 + m) * CDIM + k0 + kq,  &Bl[0][0] + lo);
        }
        __syncthreads();

        s8v ah[4], al[4], bh[4], bl[4];
        #pragma unroll
        for (int mi = 0; mi < 4; ++mi) {
            int row = wr * 64 + mi * 16 + lm;
            ah[mi] = *(const s8v*)&Ah[row][asw];
            al[mi] = *(const s8v*)&Al[row][asw];
        }
        #pragma unroll
        for (int ni = 0; ni < 4; ++ni) {
            int row = wc * 64 + ni * 16 + lm;
            bh[ni] = *(const s8v*)&Bh[row][asw];
            bl[ni] = *(const s8v*)&Bl[row][asw];
        }
        #pragma unroll
        for (int mi = 0; mi < 4; ++mi)
            #pragma unroll
            for (int ni = 0; ni < 4; ++ni) {
                acc[mi][ni] = MFMA16(ah[mi], bh[ni], acc[mi][ni]);
                acc[mi][ni] = MFMA16(ah[mi], bl[ni], acc[mi][ni]);
                acc[mi][ni] = MFMA16(al[mi], bh[ni], acc[mi][ni]);
            }
        __syncthreads();
    }

    const int th = (n0 >> 6) + wc;
    const int t3 = th / 12;
    const int h  = th - t3 * 12;
    const size_t bhb = (size_t)(b * NHEAD + h) * NTOK;

    if (t3 == 0) {
        unsigned* dst = Qp + bhb * DHEAD;
        #pragma unroll
        for (int mi = 0; mi < 4; ++mi)
            #pragma unroll
            for (int r = 0; r < 4; ++r) {
                int p = p0 + wr * 64 + mi * 16 + lg * 4 + r;
                #pragma unroll
                for (int ni = 0; ni < 4; ++ni)
                    dst[(size_t)p * DHEAD + ni * 16 + lm] = packsplit(acc[mi][ni][r] * 8.0f);
            }
    } else if (t3 == 1) {
        u16* dh = Khg + bhb * DHEAD;
        u16* dl = Klg + bhb * DHEAD;
        #pragma unroll
        for (int mi = 0; mi < 4; ++mi)
            #pragma unroll
            for (int r = 0; r < 4; ++r) {
                int p = p0 + wr * 64 + mi * 16 + lg * 4 + r;
                #pragma unroll
                for (int ni = 0; ni < 4; ++ni) {
                    int d = ni * 16 + lm;
                    int dsw = (((d >> 3) ^ (p & 7)) << 3) | (d & 7);   // SW64
                    float val = acc[mi][ni][r];
                    u16 hb = f2bf(val);
                    dh[(size_t)p * DHEAD + dsw] = hb;
                    dl[(size_t)p * DHEAD + dsw] = f2bf(val - bf2f(hb));
                }
            }
    } else {
        u16* dh = Vhg + bhb * DHEAD;
        u16* dl = Vlg + bhb * DHEAD;
        #pragma unroll
        for (int mi = 0; mi < 4; ++mi)
            #pragma unroll
            for (int r = 0; r < 4; ++r) {
                int p = p0 + wr * 64 + mi * 16 + lg * 4 + r;
                #pragma unroll
                for (int ni = 0; ni < 4; ++ni) {
                    int d = ni * 16 + lm;
                    float val = acc[mi][ni][r];
                    u16 hb = f2bf(val);
                    dh[(size_t)p * DHEAD + d] = hb;
                    dl[(size_t)p * DHEAD + d] = f2bf(val - bf2f(hb));
                }
            }
    }
}

// ---------------------------------------------------------------------------
// 1b: V planar [bh][p][d] -> Vt planar [bh][d][p], SW64-swizzled by d within
//     each 64-p window.
// ---------------------------------------------------------------------------
__launch_bounds__(256)
__global__ void vt_split(const u16* __restrict__ Vh, const u16* __restrict__ Vl,
                         u16* __restrict__ Vth, u16* __restrict__ Vtl) {
    __shared__ u16 Th[64][72];
    __shared__ u16 Tl[64][72];
    const int t  = threadIdx.x;
    const int pt = blockIdx.x;        // 16
    const int bh = blockIdx.y;        // 96

    #pragma unroll
    for (int i = 0; i < 4; ++i) {
        int idx = t + i * 256;        // [0,1024)
        int pr  = idx >> 4;
        int c4  = (idx & 15) * 4;
        size_t src = ((size_t)bh * NTOK + pt * 64 + pr) * DHEAD + c4;
        *(ushort4*)&Th[pr][c4] = *(const ushort4*)&Vh[src];
        *(ushort4*)&Tl[pr][c4] = *(const ushort4*)&Vl[src];
    }
    __syncthreads();
    #pragma unroll
    for (int i = 0; i < 4; ++i) {
        int idx   = t + i * 256;      // [0,1024)
        int plane = idx >> 9;
        int rem   = idx & 511;
        int d     = rem >> 3;
        int gp    = rem & 7;          // stored group position
        int gs    = gp ^ (d & 7);     // source p-group
        u16 tmp[8];
        #pragma unroll
        for (int j = 0; j < 8; ++j)
            tmp[j] = plane ? Tl[gs * 8 + j][d] : Th[gs * 8 + j][d];
        u16* outp = plane ? Vtl : Vth;
        size_t dst = ((size_t)bh * DHEAD + d) * NTOK + pt * 64 + gp * 8;
        *(ushort4*)&outp[dst]     = make_ushort4(tmp[0], tmp[1], tmp[2], tmp[3]);
        *(ushort4*)&outp[dst + 4] = make_ushort4(tmp[4], tmp[5], tmp[6], tmp[7]);
    }
}

// ---------------------------------------------------------------------------
// 2: MFMA flash attention.  Planar SW64 K/Vt staged via global_load_lds,
//    P single-plane bf16-hi in swizzled LDS, ctx out = split bf16 SW32.
// ---------------------------------------------------------------------------
__launch_bounds__(256)
__global__ void attn_mfma(const unsigned* __restrict__ Qp,
                          const u16* __restrict__ Khg, const u16* __restrict__ Klg,
                          const u16* __restrict__ Vth, const u16* __restrict__ Vtl,
                          u16* __restrict__ ctxh, u16* __restrict__ ctxl) {
    __shared__ u16 Kh[64][64];
    __shared__ u16 Kl[64][64];
    __shared__ u16 Vh[64][64];
    __shared__ u16 Vl[64][64];
    __shared__ u16 Ph[128][64];

    const int tid = threadIdx.x;
    const int l  = tid & 63;
    const int w  = tid >> 6;
    const int lm = l & 15;
    const int lg = l >> 4;
    const int bh = blockIdx.y;
    const int p0 = blockIdx.x * 128;

    const unsigned* Qb = Qp + (size_t)bh * NTOK * DHEAD;
    const u16* Kb_h = Khg + (size_t)bh * NTOK * DHEAD;
    const u16* Kb_l = Klg + (size_t)bh * NTOK * DHEAD;
    const u16* Vb_h = Vth + (size_t)bh * DHEAD * NTOK;
    const u16* Vb_l = Vtl + (size_t)bh * DHEAD * NTOK;

    // Q fragments (packed, pre-scaled x8)
    s8v qh[2][2], ql[2][2];
    #pragma unroll
    for (int t = 0; t < 2; ++t)
        #pragma unroll
        for (int kk = 0; kk < 2; ++kk) {
            const unsigned* src = Qb + (size_t)(p0 + w * 32 + t * 16 + lm) * DHEAD + kk * 32 + lg * 8;
            uint4 a0 = *(const uint4*)src;
            uint4 a1 = *(const uint4*)(src + 4);
            unpack8(a0, a1, qh[t][kk], ql[t][kk]);
        }

    f4v o[2][4];
    float mrun[2][4], lrun[2][4];
    #pragma unroll
    for (int t = 0; t < 2; ++t)
        #pragma unroll
        for (int c = 0; c < 4; ++c)
            o[t][c] = (f4v){0.f, 0.f, 0.f, 0.f};
    #pragma unroll
    for (int t = 0; t < 2; ++t)
        #pragma unroll
        for (int i = 0; i < 4; ++i) { mrun[t][i] = -3.0e38f; lrun[t][i] = 0.f; }

    const int fsw = (l & 7) * 8;      // 16B block within a 128B row for DMA
    const int r8  = l >> 3;           // row-in-chunk (8 rows of 128B per 1KB chunk)

    for (int kt = 0; kt < 16; ++kt) {
        __syncthreads();
        // stage K(h,l) and Vt(h,l): 8 chunks each, wave w does chunks w*2,w*2+1
        #pragma unroll
        for (int i = 0; i < 2; ++i) {
            int ch = w * 2 + i;
            int lo = ch * 512;
            size_t krow = (size_t)(kt * 64 + ch * 8 + r8) * DHEAD + fsw;
            gload16(Kb_h + krow, &Kh[0][0] + lo);
            gload16(Kb_l + krow, &Kl[0][0] + lo);
            size_t vrow = (size_t)(ch * 8 + r8) * NTOK + kt * 64 + fsw;
            gload16(Vb_h + vrow, &Vh[0][0] + lo);
            gload16(Vb_l + vrow, &Vl[0][0] + lo);
        }
        __syncthreads();

        // S = Q.K^T (bf16x3)
        f4v sa[2][4];
        #pragma unroll
        for (int t = 0; t < 2; ++t)
            #pragma unroll
            for (int c = 0; c < 4; ++c)
                sa[t][c] = (f4v){0.f, 0.f, 0.f, 0.f};

        #pragma unroll
        for (int kk = 0; kk < 2; ++kk)
            #pragma unroll
            for (int c = 0; c < 4; ++c) {
                int row = c * 16 + lm;
                int off = (((kk * 4 + lg) ^ (lm & 7))) * 8;   // SW64
                s8v kh = *(const s8v*)&Kh[row][off];
                s8v kl = *(const s8v*)&Kl[row][off];
                #pragma unroll
                for (int t = 0; t < 2; ++t) {
                    sa[t][c] = MFMA16(qh[t][kk], kh, sa[t][c]);
                    sa[t][c] = MFMA16(qh[t][kk], kl, sa[t][c]);
                    sa[t][c] = MFMA16(ql[t][kk], kh, sa[t][c]);
                }
            }

        // online softmax; write P (bf16-hi) to swizzled wave-private LDS rows
        #pragma unroll
        for (int t = 0; t < 2; ++t) {
            float f_[4];
            #pragma unroll
            for (int i = 0; i < 4; ++i) {
                float mt = fmaxf(fmaxf(sa[t][0][i], sa[t][1][i]),
                                 fmaxf(sa[t][2][i], sa[t][3][i]));
                #pragma unroll
                for (int off = 1; off < 16; off <<= 1)
                    mt = fmaxf(mt, __shfl_xor(mt, off, 16));
                float mn = fmaxf(mrun[t][i], mt);
                f_[i] = __expf(mrun[t][i] - mn);
                mrun[t][i] = mn;
            }
            #pragma unroll
            for (int i = 0; i < 4; ++i) {
                int rp = w * 32 + t * 16 + lg * 4 + i;
                float rs = 0.f;
                #pragma unroll
                for (int c = 0; c < 4; ++c) {
                    float pv = __expf(sa[t][c][i] - mrun[t][i]);
                    rs += pv;
                    int colg = c * 2 + (lm >> 3);
                    Ph[rp][((colg ^ (rp & 7)) << 3) + (lm & 7)] = f2bf(pv);
                }
                #pragma unroll
                for (int off = 1; off < 16; off <<= 1)
                    rs += __shfl_xor(rs, off, 16);
                lrun[t][i] = lrun[t][i] * f_[i] + rs;
                #pragma unroll
                for (int c = 0; c < 4; ++c)
                    o[t][c][i] *= f_[i];
            }
        }

        // O += P.V  (P rows are wave-private; compiler handles lgkmcnt)
        s8v pf[2][2];
        #pragma unroll
        for (int t = 0; t < 2; ++t)
            #pragma unroll
            for (int kk = 0; kk < 2; ++kk) {
                int row = w * 32 + t * 16 + lm;
                pf[t][kk] = *(const s8v*)&Ph[row][(((kk * 4 + lg) ^ (lm & 7))) * 8];
            }
        #pragma unroll
        for (int c = 0; c < 4; ++c)
            #pragma unroll
            for (int kk = 0; kk < 2; ++kk) {
                int row = c * 16 + lm;
                int off = (((kk * 4 + lg) ^ (lm & 7))) * 8;
                s8v vh = *(const s8v*)&Vh[row][off];
                s8v vl = *(const s8v*)&Vl[row][off];
                #pragma unroll
                for (int t = 0; t < 2; ++t) {
                    o[t][c] = MFMA16(pf[t][kk], vh, o[t][c]);
                    o[t][c] = MFMA16(pf[t][kk], vl, o[t][c]);
                }
            }
    }

    // epilogue: ctx split bf16, SW32-swizzled by row m
    const int b  = bh / NHEAD;
    const int hh = bh - b * NHEAD;
    #pragma unroll
    for (int t = 0; t < 2; ++t)
        #pragma unroll
        for (int i = 0; i < 4; ++i) {
            float inv = 1.f / lrun[t][i];
            int p = p0 + w * 32 + t * 16 + lg * 4 + i;
            size_t m = (size_t)(b * NTOK) + p;
            #pragma unroll
            for (int c = 0; c < 4; ++c) {
                int col = hh * DHEAD + c * 16 + lm;
                int csw = sw32i(p, col);
                float val = o[t][c][i] * inv;
                u16 hb = f2bf(val);
                ctxh[m * CDIM + csw] = hb;
                ctxl[m * CDIM + csw] = f2bf(val - bf2f(hb));
            }
        }
}

// ---------------------------------------------------------------------------
// 3: proj GEMM bf16x3 MFMA computing out[c'][m] = sum_k W[k][c'] ctx[m][k].
//    A = wpt [c'][k], B = ctx [m][k]; output directly in [b][c'][p] layout.
//    BM=64 (c'), BN=128 (m), BK=32; 4 waves as 2x2 (32 c' x 64 m each).
// ---------------------------------------------------------------------------
__launch_bounds__(256)
__global__ void proj_mfma(const u16* __restrict__ wph, const u16* __restrict__ wpl,
                          const u16* __restrict__ cth, const u16* __restrict__ ctl,
                          float* __restrict__ out) {
    __shared__ u16 Awh[64][32];
    __shared__ u16 Awl[64][32];
    __shared__ u16 Bch[128][32];
    __shared__ u16 Bcl[128][32];

    const int tid = threadIdx.x;
    const int l   = tid & 63;
    const int w   = tid >> 6;
    const int lm  = l & 15;
    const int lg  = l >> 4;
    const int wr  = w >> 1;
    const int wc  = w & 1;
    const int c0  = blockIdx.x * 64;
    const int m0  = blockIdx.y * 128;
    const int b   = m0 >> 10;
    const int pl0 = m0 & 1023;

    const int lrow = l >> 2;
    const int kq   = (l & 3) * 8;
    const int asw  = (lg ^ ((lm >> 1) & 3)) * 8;

    f4v acc[2][4];
    #pragma unroll
    for (int i = 0; i < 2; ++i)
        #pragma unroll
        for (int j = 0; j < 4; ++j)
            acc[i][j] = (f4v){0.f, 0.f, 0.f, 0.f};

    for (int k0 = 0; k0 < CDIM; k0 += 32) {
        {   // A: 4 chunks per plane; wave w stages chunk w
            int row = w * 16 + lrow;
            gload16(wph + (size_t)(c0 + row) * CDIM + k0 + kq, &Awh[0][0] + w * 512);
            gload16(wpl + (size_t)(c0 + row) * CDIM + k0 + kq, &Awl[0][0] + w * 512);
        }
        #pragma unroll
        for (int i = 0; i < 2; ++i) {   // B: 8 chunks per plane
            int ch = w * 2 + i;
            int row = ch * 16 + lrow;
            gload16(cth + (size_t)(m0 + row) * CDIM + k0 + kq, &Bch[0][0] + ch * 512);
            gload16(ctl + (size_t)(m0 + row) * CDIM + k0 + kq, &Bcl[0][0] + ch * 512);
        }
        __syncthreads();

        s8v ah[2], al[2], bh[4], bl[4];
        #pragma unroll
        for (int mi = 0; mi < 2; ++mi) {
            int row = wr * 32 + mi * 16 + lm;
            ah[mi] = *(const s8v*)&Awh[row][asw];
            al[mi] = *(const s8v*)&Awl[row][asw];
        }
        #pragma unroll
        for (int ni = 0; ni < 4; ++ni) {
            int row = wc * 64 + ni * 16 + lm;
            bh[ni] = *(const s8v*)&Bch[row][asw];
            bl[ni] = *(const s8v*)&Bcl[row][asw];
        }
        #pragma unroll
        for (int mi = 0; mi < 2; ++mi)
            #pragma unroll
            for (int ni = 0; ni < 4; ++ni) {
                acc[mi][ni] = MFMA16(ah[mi], bh[ni], acc[mi][ni]);
                acc[mi][ni] = MFMA16(ah[mi], bl[ni], acc[mi][ni]);
                acc[mi][ni] = MFMA16(al[mi], bh[ni], acc[mi][ni]);
            }
        __syncthreads();
    }

    #pragma unroll
    for (int mi = 0; mi < 2; ++mi)
        #pragma unroll
        for (int r = 0; r < 4; ++r) {
            int cpr = c0 + wr * 32 + mi * 16 + lg * 4 + r;
            #pragma unroll
            for (int ni = 0; ni < 4; ++ni) {
                int p = pl0 + wc * 64 + ni * 16 + lm;
                out[((size_t)b * CDIM + cpr) * NTOK + p] = acc[mi][ni][r];
            }
        }
}

// ---------------------------------------------------------------------------
extern "C" void kernel_launch(void* const* d_in, const int* in_sizes, int n_in,
                              void* d_out, int out_size, void* d_ws, size_t ws_size,
                              hipStream_t stream) {
    (void)in_sizes; (void)n_in; (void)out_size; (void)ws_size;
    const float* x      = (const float*)d_in[0];
    const float* w_qkv  = (const float*)d_in[1];
    const float* w_proj = (const float*)d_in[2];
    float* out = (float*)d_out;

    const size_t NE = (size_t)NB * NHEAD * NTOK * DHEAD;   // 6,291,456 (= NB*NTOK*CDIM)
    char* w8 = (char*)d_ws;
    unsigned* Qp = (unsigned*)w8;                  // [0, 4NE)
    u16* Khg = (u16*)(w8 + 4 * NE);                // [4NE, 6NE)
    u16* Klg = Khg + NE;                           // [6NE, 8NE)
    u16* Vhg = (u16*)(w8 + 8 * NE);                // [8NE, 10NE)   (later ctxh)
    u16* Vlg = Vhg + NE;                           // [10NE, 12NE)  (later ctxl)
    u16* xh  = (u16*)(w8 + 12 * NE);               // [12NE, 14NE)  (later Vth)
    u16* xl  = xh + NE;                            // [14NE, 16NE)  (later Vtl)
    u16* wh  = (u16*)(w8 + 16 * NE);               // C3*CDIM u16 = 3.54 MB
    u16* wl  = wh + (size_t)C3 * CDIM;             // C3*CDIM u16
    // aliases (lifetimes disjoint; peak footprint 16NE + 7.08MB = 107.75 MB):
    u16* Vth  = xh;   u16* Vtl  = xl;              // after x is dead
    u16* ctxh = Vhg;  u16* ctxl = Vlg;             // after V planar is dead
    u16* wph  = wh;   u16* wpl  = wh + (size_t)CDIM * CDIM;  // after wh/wl dead

    split_x <<<dim3(16, 12, 8), 256, 0, stream>>>(x, xh, xl);
    split_w <<<dim3(16, 48),    256, 0, stream>>>(w_qkv, wh, wl);
    qkv_mfma<<<dim3(64, 18),    256, 0, stream>>>(xh, xl, wh, wl, Qp, Khg, Klg, Vhg, Vlg);
    split_wp<<<dim3(12, 12),    256, 0, stream>>>(w_proj, wph, wpl);   // into dead wh/wl
    vt_split<<<dim3(16, 96),    256, 0, stream>>>(Vhg, Vlg, Vth, Vtl);
    attn_mfma<<<dim3(8, 96),    256, 0, stream>>>(Qp, Khg, Klg, Vth, Vtl, ctxh, ctxl);
    proj_mfma<<<dim3(12, 64),   256, 0, stream>>>(wph, wpl, ctxh, ctxl, out);
}